// Round 1
// baseline (893.760 us; speedup 1.0000x reference)
//
#include <hip/hip_runtime.h>
#include <hip/hip_bf16.h>
#include <string.h>

// Problem constants
#define BB 256
#define NNS 512
#define DDF 128
#define CC1 256
#define CC2 128
#define NPOS (BB * NNS) // 131072

typedef __attribute__((ext_vector_type(4))) float f32x4;
typedef __attribute__((ext_vector_type(8))) short bf16x8;

__device__ __forceinline__ short f2bf(float f) {
    __hip_bfloat16 h = __float2bfloat16(f);
    short s;
    __builtin_memcpy(&s, &h, 2);
    return s;
}
__device__ __forceinline__ float bf2f(short s) {
    unsigned int u = ((unsigned int)(unsigned short)s) << 16;
    float f;
    __builtin_memcpy(&f, &u, 4);
    return f;
}

#define MFMA16(a, b, c) __builtin_amdgcn_mfma_f32_16x16x32_bf16(a, b, c, 0, 0, 0)

// ---------------------------------------------------------------------------
// K0: convert W1/W2 to bf16, zero stat accumulators (ws is re-poisoned 0xAA
// before every launch, so zeroing must happen every call).
__global__ void prep_kernel(const float* __restrict__ W1, const float* __restrict__ W2,
                            short* __restrict__ W1b, short* __restrict__ W2b,
                            float* __restrict__ stats) {
    int idx = blockIdx.x * 256 + threadIdx.x;
    if (idx < CC1 * CC1) W1b[idx] = f2bf(W1[idx]);
    if (idx < CC2 * CC1) W2b[idx] = f2bf(W2[idx]);
    if (idx < 1536) stats[idx] = 0.0f;
}

// ---------------------------------------------------------------------------
// K0b: PT[b][d][j] = bf16(P[b][j][d]) so GEMM1 B-fragments are 16B contiguous.
__global__ void transposeP_kernel(const float* __restrict__ P, short* __restrict__ PT) {
    int oid = blockIdx.x * 256 + threadIdx.x; // 256*128*64 = 2,097,152 octets
    int b = oid >> 13;
    int r = oid & 8191;
    int jo = r >> 7;     // j-octet 0..63
    int d = r & 127;     // feature 0..127
    const float* p = P + (size_t)b * (NNS * DDF) + (size_t)(jo * 8) * DDF + d;
    bf16x8 v;
#pragma unroll
    for (int t = 0; t < 8; ++t) v[t] = f2bf(p[t * DDF]);
    *reinterpret_cast<bf16x8*>(PT + ((size_t)(b * DDF + d)) * NNS + jo * 8) = v;
}

// ---------------------------------------------------------------------------
// K1: masked+L1-normalized edge aggregation.
//   X[b][i][e*128 + d] = (1/max(sum_j |E[i,j]| - diag, eps)) * sum_j E[i,j]*P[j,d]
// Diagonal zeroed in-register during A-load; row |sum| accumulated during load.
// No LDS: A streams 32B-contiguous fp32 from HBM (single-use), B from PT (L2-hot).
__global__ __launch_bounds__(256) void gemm1_kernel(const float* __restrict__ dE,
                                                    const float* __restrict__ iE,
                                                    const short* __restrict__ PT,
                                                    short* __restrict__ X) {
    int bid = blockIdx.x;      // 2048 = 256 b * 2 e * 4 mtiles
    int mtb = bid & 3;
    int e = (bid >> 2) & 1;
    int b = bid >> 3;
    const float* E = (e == 0 ? dE : iE) + (size_t)b * (NNS * NNS);
    const short* PTb = PT + (size_t)b * (DDF * NNS);

    int tid = threadIdx.x;
    int lane = tid & 63, w = tid >> 6;
    int quad = lane >> 4, lr = lane & 15;
    int mh = w >> 1, nh = w & 1;
    int mbase = mtb * 128 + mh * 64;

    f32x4 zero = {0.f, 0.f, 0.f, 0.f};
    f32x4 acc[4][4];
#pragma unroll
    for (int a = 0; a < 4; ++a)
#pragma unroll
        for (int c = 0; c < 4; ++c) acc[a][c] = zero;
    float rs[4] = {0.f, 0.f, 0.f, 0.f};

    for (int kk = 0; kk < 16; ++kk) {
        int k0 = kk * 32 + quad * 8;
        bf16x8 bfr[4];
#pragma unroll
        for (int nt = 0; nt < 4; ++nt) {
            int n = nh * 64 + nt * 16 + lr;
            bfr[nt] = *reinterpret_cast<const bf16x8*>(&PTb[(size_t)n * NNS + k0]);
        }
#pragma unroll
        for (int mt = 0; mt < 4; ++mt) {
            int i = mbase + mt * 16 + lr;
            const float* rp = &E[(size_t)i * NNS + k0];
            float4 v0 = *reinterpret_cast<const float4*>(rp);
            float4 v1 = *reinterpret_cast<const float4*>(rp + 4);
            float a8[8] = {v0.x, v0.y, v0.z, v0.w, v1.x, v1.y, v1.z, v1.w};
#pragma unroll
            for (int t = 0; t < 8; ++t)
                if (k0 + t == i) a8[t] = 0.0f; // diag mask
#pragma unroll
            for (int t = 0; t < 8; ++t) rs[mt] += fabsf(a8[t]); // L1 row sum
            bf16x8 af;
#pragma unroll
            for (int t = 0; t < 8; ++t) af[t] = f2bf(a8[t]);
#pragma unroll
            for (int nt = 0; nt < 4; ++nt) acc[mt][nt] = MFMA16(af, bfr[nt], acc[mt][nt]);
        }
    }

    // full row sums: combine the 4 k-octet partials (quads)
    float inv[4];
#pragma unroll
    for (int mt = 0; mt < 4; ++mt) {
        float s = rs[mt];
        s += __shfl_xor(s, 16, 64);
        s += __shfl_xor(s, 32, 64);
        inv[mt] = 1.0f / fmaxf(s, 1e-12f); // lane holds inv for row (lane&15)
    }
#pragma unroll
    for (int mt = 0; mt < 4; ++mt) {
        float ir[4];
#pragma unroll
        for (int r = 0; r < 4; ++r) ir[r] = __shfl(inv[mt], quad * 4 + r, 64);
#pragma unroll
        for (int nt = 0; nt < 4; ++nt) {
            int col = e * 128 + nh * 64 + nt * 16 + lr;
#pragma unroll
            for (int r = 0; r < 4; ++r) {
                int row = mbase + mt * 16 + quad * 4 + r;
                X[((size_t)b * NNS + row) * CC1 + col] = f2bf(acc[mt][nt][r] * ir[r]);
            }
        }
    }
}

// ---------------------------------------------------------------------------
// K2: Y1[pos][o] = sum_c X[pos][c] * W1[o][c]; accumulate BN1 stats.
__global__ __launch_bounds__(256) void gemm2_kernel(const short* __restrict__ X,
                                                    const short* __restrict__ W1b,
                                                    short* __restrict__ Y1,
                                                    float* __restrict__ sum1,
                                                    float* __restrict__ sumsq1) {
    int bid = blockIdx.x; // 2048 = 1024 pos-tiles * 2 och-tiles
    int ocb = (bid & 1) * 128;
    int pt = bid >> 1;
    int tid = threadIdx.x;
    int lane = tid & 63, w = tid >> 6;
    int quad = lane >> 4, lr = lane & 15;
    int mh = w >> 1, nh = w & 1;
    int pbase = pt * 128 + mh * 64;

    f32x4 zero = {0.f, 0.f, 0.f, 0.f};
    f32x4 acc[4][4];
#pragma unroll
    for (int a = 0; a < 4; ++a)
#pragma unroll
        for (int c = 0; c < 4; ++c) acc[a][c] = zero;

    for (int kk = 0; kk < 8; ++kk) {
        int k0 = kk * 32 + quad * 8;
        bf16x8 bfr[4];
#pragma unroll
        for (int nt = 0; nt < 4; ++nt) {
            int o = ocb + nh * 64 + nt * 16 + lr;
            bfr[nt] = *reinterpret_cast<const bf16x8*>(&W1b[(size_t)o * CC1 + k0]);
        }
#pragma unroll
        for (int mt = 0; mt < 4; ++mt) {
            int pos = pbase + mt * 16 + lr;
            bf16x8 af = *reinterpret_cast<const bf16x8*>(&X[(size_t)pos * CC1 + k0]);
#pragma unroll
            for (int nt = 0; nt < 4; ++nt) acc[mt][nt] = MFMA16(af, bfr[nt], acc[mt][nt]);
        }
    }
#pragma unroll
    for (int nt = 0; nt < 4; ++nt) {
        int o = ocb + nh * 64 + nt * 16 + lr;
        float s = 0.f, q = 0.f;
#pragma unroll
        for (int mt = 0; mt < 4; ++mt)
#pragma unroll
            for (int r = 0; r < 4; ++r) {
                float v = acc[mt][nt][r];
                s += v;
                q += v * v;
            }
        s += __shfl_xor(s, 16, 64); s += __shfl_xor(s, 32, 64);
        q += __shfl_xor(q, 16, 64); q += __shfl_xor(q, 32, 64);
        if (lane < 16) {
            atomicAdd(&sum1[o], s);
            atomicAdd(&sumsq1[o], q);
        }
#pragma unroll
        for (int mt = 0; mt < 4; ++mt)
#pragma unroll
            for (int r = 0; r < 4; ++r) {
                int pos = pbase + mt * 16 + quad * 4 + r;
                Y1[(size_t)pos * CC1 + o] = f2bf(acc[mt][nt][r]);
            }
    }
}

// ---------------------------------------------------------------------------
// BN finalize: scale = g*rsqrt(var+eps), shift = b - mean*scale
__global__ void finalize_kernel(const float* __restrict__ sum, const float* __restrict__ sumsq,
                                const float* __restrict__ g, const float* __restrict__ b,
                                float* __restrict__ scale, float* __restrict__ shift, int C) {
    int i = threadIdx.x;
    if (i < C) {
        const float invM = 1.0f / (float)NPOS;
        float m = sum[i] * invM;
        float v = sumsq[i] * invM - m * m;
        float s = g[i] * rsqrtf(v + 1e-5f);
        scale[i] = s;
        shift[i] = b[i] - m * s;
    }
}

// ---------------------------------------------------------------------------
// K3: Y2[pos][o] = sum_c lrelu(bn1(Y1[pos][c])) * W2[o][c]; accumulate BN2 stats.
__global__ __launch_bounds__(256) void gemm3_kernel(const short* __restrict__ Y1,
                                                    const short* __restrict__ W2b,
                                                    const float* __restrict__ scale1,
                                                    const float* __restrict__ shift1,
                                                    float* __restrict__ Y2,
                                                    float* __restrict__ sum2,
                                                    float* __restrict__ sumsq2) {
    __shared__ __align__(16) float ssc[CC1];
    __shared__ __align__(16) float ssh[CC1];
    ssc[threadIdx.x] = scale1[threadIdx.x];
    ssh[threadIdx.x] = shift1[threadIdx.x];
    __syncthreads();

    int pt = blockIdx.x; // 1024 pos-tiles, full 128 och per block
    int tid = threadIdx.x;
    int lane = tid & 63, w = tid >> 6;
    int quad = lane >> 4, lr = lane & 15;
    int mh = w >> 1, nh = w & 1;
    int pbase = pt * 128 + mh * 64;

    f32x4 zero = {0.f, 0.f, 0.f, 0.f};
    f32x4 acc[4][4];
#pragma unroll
    for (int a = 0; a < 4; ++a)
#pragma unroll
        for (int c = 0; c < 4; ++c) acc[a][c] = zero;

    for (int kk = 0; kk < 8; ++kk) {
        int k0 = kk * 32 + quad * 8;
        bf16x8 bfr[4];
#pragma unroll
        for (int nt = 0; nt < 4; ++nt) {
            int o = nh * 64 + nt * 16 + lr;
            bfr[nt] = *reinterpret_cast<const bf16x8*>(&W2b[(size_t)o * CC1 + k0]);
        }
        float4 sc0 = *reinterpret_cast<const float4*>(&ssc[k0]);
        float4 sc1 = *reinterpret_cast<const float4*>(&ssc[k0 + 4]);
        float4 sh0 = *reinterpret_cast<const float4*>(&ssh[k0]);
        float4 sh1 = *reinterpret_cast<const float4*>(&ssh[k0 + 4]);
        float scv[8] = {sc0.x, sc0.y, sc0.z, sc0.w, sc1.x, sc1.y, sc1.z, sc1.w};
        float shv[8] = {sh0.x, sh0.y, sh0.z, sh0.w, sh1.x, sh1.y, sh1.z, sh1.w};
#pragma unroll
        for (int mt = 0; mt < 4; ++mt) {
            int pos = pbase + mt * 16 + lr;
            bf16x8 raw = *reinterpret_cast<const bf16x8*>(&Y1[(size_t)pos * CC1 + k0]);
            bf16x8 af;
#pragma unroll
            for (int t = 0; t < 8; ++t) {
                float v = bf2f(raw[t]) * scv[t] + shv[t];
                v = fmaxf(v, 0.01f * v); // leaky relu
                af[t] = f2bf(v);
            }
#pragma unroll
            for (int nt = 0; nt < 4; ++nt) acc[mt][nt] = MFMA16(af, bfr[nt], acc[mt][nt]);
        }
    }
#pragma unroll
    for (int nt = 0; nt < 4; ++nt) {
        int o = nh * 64 + nt * 16 + lr;
        float s = 0.f, q = 0.f;
#pragma unroll
        for (int mt = 0; mt < 4; ++mt)
#pragma unroll
            for (int r = 0; r < 4; ++r) {
                float v = acc[mt][nt][r];
                s += v;
                q += v * v;
            }
        s += __shfl_xor(s, 16, 64); s += __shfl_xor(s, 32, 64);
        q += __shfl_xor(q, 16, 64); q += __shfl_xor(q, 32, 64);
        if (lane < 16) {
            atomicAdd(&sum2[o], s);
            atomicAdd(&sumsq2[o], q);
        }
#pragma unroll
        for (int mt = 0; mt < 4; ++mt)
#pragma unroll
            for (int r = 0; r < 4; ++r) {
                int pos = pbase + mt * 16 + quad * 4 + r;
                Y2[(size_t)pos * CC2 + o] = acc[mt][nt][r];
            }
    }
}

// ---------------------------------------------------------------------------
// K4: out = lrelu(bn2(Y2)), fp32, (B,N,128) layout.
__global__ void apply2_kernel(const float* __restrict__ Y2, const float* __restrict__ scale2,
                              const float* __restrict__ shift2, float* __restrict__ out) {
    size_t gid = (size_t)blockIdx.x * 256 + threadIdx.x;
    size_t base = gid * 4;
    float4 y = *reinterpret_cast<const float4*>(&Y2[base]);
    int o = (int)(base & 127);
    float4 sc = *reinterpret_cast<const float4*>(&scale2[o]);
    float4 sh = *reinterpret_cast<const float4*>(&shift2[o]);
    float4 t;
    t.x = y.x * sc.x + sh.x; t.x = fmaxf(t.x, 0.01f * t.x);
    t.y = y.y * sc.y + sh.y; t.y = fmaxf(t.y, 0.01f * t.y);
    t.z = y.z * sc.z + sh.z; t.z = fmaxf(t.z, 0.01f * t.z);
    t.w = y.w * sc.w + sh.w; t.w = fmaxf(t.w, 0.01f * t.w);
    *reinterpret_cast<float4*>(&out[base]) = t;
}

// ---------------------------------------------------------------------------
extern "C" void kernel_launch(void* const* d_in, const int* in_sizes, int n_in,
                              void* d_out, int out_size, void* d_ws, size_t ws_size,
                              hipStream_t stream) {
    const float* dE = (const float*)d_in[0];
    const float* iE = (const float*)d_in[1];
    const float* P  = (const float*)d_in[2];
    const float* W1 = (const float*)d_in[3];
    const float* g1 = (const float*)d_in[4];
    const float* b1 = (const float*)d_in[5];
    const float* W2 = (const float*)d_in[6];
    const float* g2 = (const float*)d_in[7];
    const float* b2 = (const float*)d_in[8];
    float* out = (float*)d_out;
    char* ws = (char*)d_ws;

    // Workspace layout (~160.2 MiB total):
    short* PT  = (short*)(ws + 0);           // 32 MiB  bf16 P^T [b][d][j]
    short* X   = (short*)(ws + 33554432);    // 64 MiB  bf16 aggr concat [pos][256]
    short* Y1  = (short*)(ws + 100663296);   // 64 MiB  bf16 conv1 raw  [pos][256]
    float* Y2  = (float*)(ws + 33554432);    // 64 MiB  fp32 conv2 raw  [pos][128] (aliases dead X)
    short* W1b = (short*)(ws + 167772160);   // 128 KiB
    short* W2b = (short*)(ws + 167903232);   // 64 KiB
    float* st  = (float*)(ws + 167968768);   // 6 KiB stats
    float* sum1 = st,        * sumsq1 = st + 256, * scale1 = st + 512,  * shift1 = st + 768;
    float* sum2 = st + 1024, * sumsq2 = st + 1152, * scale2 = st + 1280, * shift2 = st + 1408;

    prep_kernel<<<256, 256, 0, stream>>>(W1, W2, W1b, W2b, st);
    transposeP_kernel<<<8192, 256, 0, stream>>>(P, PT);
    gemm1_kernel<<<2048, 256, 0, stream>>>(dE, iE, PT, X);
    gemm2_kernel<<<2048, 256, 0, stream>>>(X, W1b, Y1, sum1, sumsq1);
    finalize_kernel<<<1, 256, 0, stream>>>(sum1, sumsq1, g1, b1, scale1, shift1, CC1);
    gemm3_kernel<<<1024, 256, 0, stream>>>(Y1, W2b, scale1, shift1, Y2, sum2, sumsq2);
    finalize_kernel<<<1, 128, 0, stream>>>(sum2, sumsq2, g2, b2, scale2, shift2, CC2);
    apply2_kernel<<<16384, 256, 0, stream>>>(Y2, scale2, shift2, out);
}

// Round 2
// 783.593 us; speedup vs baseline: 1.1406x; 1.1406x over previous
//
#include <hip/hip_runtime.h>
#include <hip/hip_bf16.h>
#include <string.h>

// Problem constants
#define BB 256
#define NNS 512
#define DDF 128
#define CC1 256
#define CC2 128
#define NPOS (BB * NNS) // 131072

typedef __attribute__((ext_vector_type(4))) float f32x4;
typedef __attribute__((ext_vector_type(8))) short bf16x8;

__device__ __forceinline__ short f2bf(float f) {
    __hip_bfloat16 h = __float2bfloat16(f);
    short s;
    __builtin_memcpy(&s, &h, 2);
    return s;
}
__device__ __forceinline__ float bf2f(short s) {
    unsigned int u = ((unsigned int)(unsigned short)s) << 16;
    float f;
    __builtin_memcpy(&f, &u, 4);
    return f;
}
__device__ __forceinline__ unsigned int pk2bf(float a, float b) {
    float2 t; t.x = a; t.y = b;
    __hip_bfloat162 h = __float22bfloat162_rn(t);
    unsigned int u;
    __builtin_memcpy(&u, &h, 4);
    return u;
}

// async global->LDS, 16B per lane. LDS dest = wave-uniform base + lane*16.
__device__ __forceinline__ void gload_lds16(const void* g, void* l) {
    __builtin_amdgcn_global_load_lds(
        (const __attribute__((address_space(1))) unsigned int*)g,
        (__attribute__((address_space(3))) unsigned int*)l, 16, 0, 0);
}

#define MFMA16(a, b, c) __builtin_amdgcn_mfma_f32_16x16x32_bf16(a, b, c, 0, 0, 0)

// ---------------------------------------------------------------------------
// K0: convert W1/W2 to bf16, zero stat accumulators (ws re-poisoned each call).
__global__ void prep_kernel(const float* __restrict__ W1, const float* __restrict__ W2,
                            short* __restrict__ W1b, short* __restrict__ W2b,
                            float* __restrict__ stats) {
    int idx = blockIdx.x * 256 + threadIdx.x;
    if (idx < CC1 * CC1) W1b[idx] = f2bf(W1[idx]);
    if (idx < CC2 * CC1) W2b[idx] = f2bf(W2[idx]);
    if (idx < 1536) stats[idx] = 0.0f;
}

// ---------------------------------------------------------------------------
// K0b: PT[b][d][j] = bf16(P[b][j][d]). LDS-tiled so reads AND writes coalesce.
// Grid: 2048 = 256 b * 8 j-tiles of 64. Tile: 64 j x 128 d.
__global__ __launch_bounds__(256) void transposeP_kernel(const float* __restrict__ P,
                                                         short* __restrict__ PT) {
    __shared__ float tp[64 * 132]; // pad 132: bank = (j + d) % 32 -> 2-way max
    int b = blockIdx.x >> 3;
    int j0 = (blockIdx.x & 7) * 64;
    int t = threadIdx.x;
    const float* Pb = P + ((size_t)b * NNS + j0) * DDF;
    // load 64x128 fp32: 8 passes, each 8 j-rows x 128 d (float4/lane)
    int jr = t >> 5, dc = (t & 31) * 4;
#pragma unroll
    for (int p = 0; p < 8; ++p) {
        int j = p * 8 + jr;
        float4 v = *reinterpret_cast<const float4*>(&Pb[(size_t)j * DDF + dc]);
        *reinterpret_cast<float4*>(&tp[j * 132 + dc]) = v;
    }
    __syncthreads();
    // write: row d gets 64 j as bf16 (128B contiguous per d-row)
    int jo = t & 7;
#pragma unroll
    for (int p = 0; p < 4; ++p) {
        int d = p * 32 + (t >> 3);
        bf16x8 v;
#pragma unroll
        for (int s = 0; s < 8; ++s) v[s] = f2bf(tp[(jo * 8 + s) * 132 + d]);
        *reinterpret_cast<bf16x8*>(&PT[((size_t)(b * DDF + d)) * NNS + j0 + jo * 8]) = v;
    }
}

// ---------------------------------------------------------------------------
// K1: masked + L1-normalized edge aggregation.
//   X[b][i][e*128+d] = (1/max(sum_j |E[i,j]|, eps)) * sum_j E~[i,j]*P[j,d]
// E staged async into LDS (double-buffered, XOR-swizzled 16B slots);
// diag mask + |row sum| + bf16 pack done on the LDS->reg path.
__global__ __launch_bounds__(256) void gemm1_kernel(const float* __restrict__ dE,
                                                    const float* __restrict__ iE,
                                                    const short* __restrict__ PT,
                                                    short* __restrict__ X) {
    __shared__ __align__(16) float tA[2][4096]; // 2 x 16KB: 128 rows x 32 cols fp32
    int bid = blockIdx.x; // 2048 = 256 b * 2 e * 4 mtiles
    int mtb = bid & 3;
    int e = (bid >> 2) & 1;
    int b = bid >> 3;
    const float* E = (e == 0 ? dE : iE) + (size_t)b * (NNS * NNS);
    const short* PTb = PT + (size_t)b * (DDF * NNS);

    int tid = threadIdx.x;
    int lane = tid & 63, w = tid >> 6;
    int quad = lane >> 4, lr = lane & 15;
    int mh = w >> 1, nh = w & 1;
    int mbase = mtb * 128;
    int mwave = mh * 64;

    // staging decode for this thread (same every kk): 4 issues x 256 slots
    int srow[4], scol[4];
#pragma unroll
    for (int i = 0; i < 4; ++i) {
        int rl = i * 32 + (tid >> 3);
        srow[i] = rl;
        scol[i] = (tid & 7) ^ (rl & 7);
    }

    f32x4 zero = {0.f, 0.f, 0.f, 0.f};
    f32x4 acc[4][4];
#pragma unroll
    for (int a = 0; a < 4; ++a)
#pragma unroll
        for (int c = 0; c < 4; ++c) acc[a][c] = zero;
    float rs[4] = {0.f, 0.f, 0.f, 0.f};

    // prologue: stage kk=0 into buf 0
#pragma unroll
    for (int i = 0; i < 4; ++i)
        gload_lds16(&E[(size_t)(mbase + srow[i]) * NNS + scol[i] * 4],
                    (char*)&tA[0][0] + i * 4096 + w * 1024);
    __syncthreads();

    for (int kk = 0; kk < 16; ++kk) {
        const float* cur = &tA[kk & 1][0];
        if (kk < 15) {
            float* nxt = &tA[(kk + 1) & 1][0];
            int kc = (kk + 1) * 32;
#pragma unroll
            for (int i = 0; i < 4; ++i)
                gload_lds16(&E[(size_t)(mbase + srow[i]) * NNS + kc + scol[i] * 4],
                            (char*)nxt + i * 4096 + w * 1024);
        }
        int k0 = kk * 32 + quad * 8;
        bf16x8 bfr[4];
#pragma unroll
        for (int nt = 0; nt < 4; ++nt) {
            int n = nh * 64 + nt * 16 + lr;
            bfr[nt] = *reinterpret_cast<const bf16x8*>(&PTb[(size_t)n * NNS + k0]);
        }
#pragma unroll
        for (int mt = 0; mt < 4; ++mt) {
            int rl = mwave + mt * 16 + lr;          // row within 128-tile
            int i = mbase + rl;                     // global row
            int sw = rl & 7;
            int s0 = rl * 8 + ((quad * 2) ^ sw);
            int s1 = rl * 8 + ((quad * 2 + 1) ^ sw);
            float4 v0 = *reinterpret_cast<const float4*>(&cur[s0 * 4]);
            float4 v1 = *reinterpret_cast<const float4*>(&cur[s1 * 4]);
            float a8[8] = {v0.x, v0.y, v0.z, v0.w, v1.x, v1.y, v1.z, v1.w};
#pragma unroll
            for (int tt = 0; tt < 8; ++tt)
                if (k0 + tt == i) a8[tt] = 0.0f; // diag mask
#pragma unroll
            for (int tt = 0; tt < 8; ++tt) rs[mt] += fabsf(a8[tt]); // L1 row sum
            union { bf16x8 v; unsigned int u[4]; } af;
#pragma unroll
            for (int tt = 0; tt < 4; ++tt) af.u[tt] = pk2bf(a8[2 * tt], a8[2 * tt + 1]);
#pragma unroll
            for (int nt = 0; nt < 4; ++nt) acc[mt][nt] = MFMA16(af.v, bfr[nt], acc[mt][nt]);
        }
        __syncthreads();
    }

    // full row sums: combine the 4 k-octet partials (quads)
    float inv[4];
#pragma unroll
    for (int mt = 0; mt < 4; ++mt) {
        float s = rs[mt];
        s += __shfl_xor(s, 16, 64);
        s += __shfl_xor(s, 32, 64);
        inv[mt] = 1.0f / fmaxf(s, 1e-12f);
    }
#pragma unroll
    for (int mt = 0; mt < 4; ++mt) {
        float ir[4];
#pragma unroll
        for (int r = 0; r < 4; ++r) ir[r] = __shfl(inv[mt], quad * 4 + r, 64);
#pragma unroll
        for (int nt = 0; nt < 4; ++nt) {
            int col = e * 128 + nh * 64 + nt * 16 + lr;
#pragma unroll
            for (int r = 0; r < 4; ++r) {
                int row = mbase + mwave + mt * 16 + quad * 4 + r;
                X[((size_t)b * NNS + row) * CC1 + col] = f2bf(acc[mt][nt][r] * ir[r]);
            }
        }
    }
}

// ---------------------------------------------------------------------------
// K2: Y1[pos][o] = sum_c X[pos][c]*W1[o][c]; BN1 stats. 512 thr: 128 pos x 256 o.
__global__ __launch_bounds__(512) void gemm2_kernel(const short* __restrict__ X,
                                                    const short* __restrict__ W1b,
                                                    short* __restrict__ Y1,
                                                    float* __restrict__ sum1,
                                                    float* __restrict__ sumsq1) {
    __shared__ __align__(16) short tA[2][4096]; // 2 x 8KB: 128 rows x 32 cols bf16
    int pbase = blockIdx.x * 128; // 1024 blocks
    int tid = threadIdx.x;
    int lane = tid & 63, w = tid >> 6;
    int quad = lane >> 4, lr = lane & 15;
    int mh = w >> 2, nh = w & 3;

    // staging decode: 512 slots of 16B = 8KB; pair = 2 rows (8 slots)
    int spair = tid >> 3;
    int sl3 = (tid & 7) ^ (spair & 7);
    int srow = spair * 2 + (sl3 >> 2);
    int scol = sl3 & 3; // 16B units within row

    f32x4 zero = {0.f, 0.f, 0.f, 0.f};
    f32x4 acc[4][4];
#pragma unroll
    for (int a = 0; a < 4; ++a)
#pragma unroll
        for (int c = 0; c < 4; ++c) acc[a][c] = zero;

    gload_lds16(&X[(size_t)(pbase + srow) * CC1 + scol * 8], (char*)&tA[0][0] + w * 1024);
    __syncthreads();

    for (int kk = 0; kk < 8; ++kk) {
        const short* cur = &tA[kk & 1][0];
        if (kk < 7)
            gload_lds16(&X[(size_t)(pbase + srow) * CC1 + (kk + 1) * 32 + scol * 8],
                        (char*)&tA[(kk + 1) & 1][0] + w * 1024);
        int k0 = kk * 32 + quad * 8;
        bf16x8 bfr[4];
#pragma unroll
        for (int nt = 0; nt < 4; ++nt) {
            int o = nh * 64 + nt * 16 + lr;
            bfr[nt] = *reinterpret_cast<const bf16x8*>(&W1b[(size_t)o * CC1 + k0]);
        }
#pragma unroll
        for (int mt = 0; mt < 4; ++mt) {
            int rl = mh * 64 + mt * 16 + lr;
            int pair = rl >> 1;
            int s3 = ((rl & 1) << 2) | quad;
            int phys = pair * 8 + (s3 ^ (pair & 7));
            bf16x8 af = *reinterpret_cast<const bf16x8*>(&cur[phys * 8]);
#pragma unroll
            for (int nt = 0; nt < 4; ++nt) acc[mt][nt] = MFMA16(af, bfr[nt], acc[mt][nt]);
        }
        __syncthreads();
    }
#pragma unroll
    for (int nt = 0; nt < 4; ++nt) {
        int o = nh * 64 + nt * 16 + lr;
        float s = 0.f, q = 0.f;
#pragma unroll
        for (int mt = 0; mt < 4; ++mt)
#pragma unroll
            for (int r = 0; r < 4; ++r) {
                float v = acc[mt][nt][r];
                s += v;
                q += v * v;
            }
        s += __shfl_xor(s, 16, 64); s += __shfl_xor(s, 32, 64);
        q += __shfl_xor(q, 16, 64); q += __shfl_xor(q, 32, 64);
        if (lane < 16) {
            atomicAdd(&sum1[o], s);
            atomicAdd(&sumsq1[o], q);
        }
#pragma unroll
        for (int mt = 0; mt < 4; ++mt)
#pragma unroll
            for (int r = 0; r < 4; ++r) {
                int pos = pbase + mh * 64 + mt * 16 + quad * 4 + r;
                Y1[(size_t)pos * CC1 + o] = f2bf(acc[mt][nt][r]);
            }
    }
}

// ---------------------------------------------------------------------------
// BN finalize: scale = g*rsqrt(var+eps), shift = b - mean*scale
__global__ void finalize_kernel(const float* __restrict__ sum, const float* __restrict__ sumsq,
                                const float* __restrict__ g, const float* __restrict__ b,
                                float* __restrict__ scale, float* __restrict__ shift, int C) {
    int i = threadIdx.x;
    if (i < C) {
        const float invM = 1.0f / (float)NPOS;
        float m = sum[i] * invM;
        float v = sumsq[i] * invM - m * m;
        float s = g[i] * rsqrtf(v + 1e-5f);
        scale[i] = s;
        shift[i] = b[i] - m * s;
    }
}

// ---------------------------------------------------------------------------
// K3: Y2[pos][o] = sum_c lrelu(bn1(Y1[pos][c]))*W2[o][c]; BN2 stats.
__global__ __launch_bounds__(256) void gemm3_kernel(const short* __restrict__ Y1,
                                                    const short* __restrict__ W2b,
                                                    const float* __restrict__ scale1,
                                                    const float* __restrict__ shift1,
                                                    float* __restrict__ Y2,
                                                    float* __restrict__ sum2,
                                                    float* __restrict__ sumsq2) {
    __shared__ __align__(16) short tA[2][4096]; // 2 x 8KB
    __shared__ __align__(16) float ssc[CC1];
    __shared__ __align__(16) float ssh[CC1];
    ssc[threadIdx.x] = scale1[threadIdx.x];
    ssh[threadIdx.x] = shift1[threadIdx.x];

    int pbase = blockIdx.x * 128; // 1024 blocks
    int tid = threadIdx.x;
    int lane = tid & 63, w = tid >> 6;
    int quad = lane >> 4, lr = lane & 15;
    int mh = w >> 1, nh = w & 1;

    // staging decode: 2 issues x 256 slots
    int srow[2], scol[2];
#pragma unroll
    for (int i = 0; i < 2; ++i) {
        int slot = i * 256 + tid;
        int pair = slot >> 3;
        int s3 = (slot & 7) ^ (pair & 7);
        srow[i] = pair * 2 + (s3 >> 2);
        scol[i] = s3 & 3;
    }

    f32x4 zero = {0.f, 0.f, 0.f, 0.f};
    f32x4 acc[4][4];
#pragma unroll
    for (int a = 0; a < 4; ++a)
#pragma unroll
        for (int c = 0; c < 4; ++c) acc[a][c] = zero;

#pragma unroll
    for (int i = 0; i < 2; ++i)
        gload_lds16(&Y1[(size_t)(pbase + srow[i]) * CC1 + scol[i] * 8],
                    (char*)&tA[0][0] + i * 4096 + w * 1024);
    __syncthreads();

    for (int kk = 0; kk < 8; ++kk) {
        const short* cur = &tA[kk & 1][0];
        if (kk < 7) {
#pragma unroll
            for (int i = 0; i < 2; ++i)
                gload_lds16(&Y1[(size_t)(pbase + srow[i]) * CC1 + (kk + 1) * 32 + scol[i] * 8],
                            (char*)&tA[(kk + 1) & 1][0] + i * 4096 + w * 1024);
        }
        int k0 = kk * 32 + quad * 8;
        bf16x8 bfr[4];
#pragma unroll
        for (int nt = 0; nt < 4; ++nt) {
            int o = nh * 64 + nt * 16 + lr;
            bfr[nt] = *reinterpret_cast<const bf16x8*>(&W2b[(size_t)o * CC1 + k0]);
        }
        float4 sc0 = *reinterpret_cast<const float4*>(&ssc[k0]);
        float4 sc1 = *reinterpret_cast<const float4*>(&ssc[k0 + 4]);
        float4 sh0 = *reinterpret_cast<const float4*>(&ssh[k0]);
        float4 sh1 = *reinterpret_cast<const float4*>(&ssh[k0 + 4]);
        float scv[8] = {sc0.x, sc0.y, sc0.z, sc0.w, sc1.x, sc1.y, sc1.z, sc1.w};
        float shv[8] = {sh0.x, sh0.y, sh0.z, sh0.w, sh1.x, sh1.y, sh1.z, sh1.w};
#pragma unroll
        for (int mt = 0; mt < 4; ++mt) {
            int rl = mh * 64 + mt * 16 + lr;
            int pair = rl >> 1;
            int s3 = ((rl & 1) << 2) | quad;
            int phys = pair * 8 + (s3 ^ (pair & 7));
            bf16x8 raw = *reinterpret_cast<const bf16x8*>(&cur[phys * 8]);
            union { bf16x8 v; unsigned int u[4]; } af;
#pragma unroll
            for (int tt = 0; tt < 4; ++tt) {
                float va = bf2f(raw[2 * tt]) * scv[2 * tt] + shv[2 * tt];
                va = fmaxf(va, 0.01f * va);
                float vb = bf2f(raw[2 * tt + 1]) * scv[2 * tt + 1] + shv[2 * tt + 1];
                vb = fmaxf(vb, 0.01f * vb);
                af.u[tt] = pk2bf(va, vb);
            }
#pragma unroll
            for (int nt = 0; nt < 4; ++nt) acc[mt][nt] = MFMA16(af.v, bfr[nt], acc[mt][nt]);
        }
        __syncthreads();
    }
#pragma unroll
    for (int nt = 0; nt < 4; ++nt) {
        int o = nh * 64 + nt * 16 + lr;
        float s = 0.f, q = 0.f;
#pragma unroll
        for (int mt = 0; mt < 4; ++mt)
#pragma unroll
            for (int r = 0; r < 4; ++r) {
                float v = acc[mt][nt][r];
                s += v;
                q += v * v;
            }
        s += __shfl_xor(s, 16, 64); s += __shfl_xor(s, 32, 64);
        q += __shfl_xor(q, 16, 64); q += __shfl_xor(q, 32, 64);
        if (lane < 16) {
            atomicAdd(&sum2[o], s);
            atomicAdd(&sumsq2[o], q);
        }
#pragma unroll
        for (int mt = 0; mt < 4; ++mt)
#pragma unroll
            for (int r = 0; r < 4; ++r) {
                int pos = pbase + mh * 64 + mt * 16 + quad * 4 + r;
                Y2[(size_t)pos * CC2 + o] = acc[mt][nt][r];
            }
    }
}

// ---------------------------------------------------------------------------
// K4: out = lrelu(bn2(Y2)), fp32, (B,N,128) layout.
__global__ void apply2_kernel(const float* __restrict__ Y2, const float* __restrict__ scale2,
                              const float* __restrict__ shift2, float* __restrict__ out) {
    size_t gid = (size_t)blockIdx.x * 256 + threadIdx.x;
    size_t base = gid * 4;
    float4 y = *reinterpret_cast<const float4*>(&Y2[base]);
    int o = (int)(base & 127);
    float4 sc = *reinterpret_cast<const float4*>(&scale2[o]);
    float4 sh = *reinterpret_cast<const float4*>(&shift2[o]);
    float4 t;
    t.x = y.x * sc.x + sh.x; t.x = fmaxf(t.x, 0.01f * t.x);
    t.y = y.y * sc.y + sh.y; t.y = fmaxf(t.y, 0.01f * t.y);
    t.z = y.z * sc.z + sh.z; t.z = fmaxf(t.z, 0.01f * t.z);
    t.w = y.w * sc.w + sh.w; t.w = fmaxf(t.w, 0.01f * t.w);
    *reinterpret_cast<float4*>(&out[base]) = t;
}

// ---------------------------------------------------------------------------
extern "C" void kernel_launch(void* const* d_in, const int* in_sizes, int n_in,
                              void* d_out, int out_size, void* d_ws, size_t ws_size,
                              hipStream_t stream) {
    const float* dE = (const float*)d_in[0];
    const float* iE = (const float*)d_in[1];
    const float* P  = (const float*)d_in[2];
    const float* W1 = (const float*)d_in[3];
    const float* g1 = (const float*)d_in[4];
    const float* b1 = (const float*)d_in[5];
    const float* W2 = (const float*)d_in[6];
    const float* g2 = (const float*)d_in[7];
    const float* b2 = (const float*)d_in[8];
    float* out = (float*)d_out;
    char* ws = (char*)d_ws;

    // Workspace layout (~160.2 MiB total):
    short* PT  = (short*)(ws + 0);           // 32 MiB  bf16 P^T [b][d][j]
    short* X   = (short*)(ws + 33554432);    // 64 MiB  bf16 aggr concat [pos][256]
    short* Y1  = (short*)(ws + 100663296);   // 64 MiB  bf16 conv1 raw  [pos][256]
    float* Y2  = (float*)(ws + 33554432);    // 64 MiB  fp32 conv2 raw  [pos][128] (aliases dead X)
    short* W1b = (short*)(ws + 167772160);   // 128 KiB
    short* W2b = (short*)(ws + 167903232);   // 64 KiB
    float* st  = (float*)(ws + 167968768);   // 6 KiB stats
    float* sum1 = st,        * sumsq1 = st + 256, * scale1 = st + 512,  * shift1 = st + 768;
    float* sum2 = st + 1024, * sumsq2 = st + 1152, * scale2 = st + 1280, * shift2 = st + 1408;

    prep_kernel<<<256, 256, 0, stream>>>(W1, W2, W1b, W2b, st);
    transposeP_kernel<<<2048, 256, 0, stream>>>(P, PT);
    gemm1_kernel<<<2048, 256, 0, stream>>>(dE, iE, PT, X);
    gemm2_kernel<<<1024, 512, 0, stream>>>(X, W1b, Y1, sum1, sumsq1);
    finalize_kernel<<<1, 256, 0, stream>>>(sum1, sumsq1, g1, b1, scale1, shift1, CC1);
    gemm3_kernel<<<1024, 256, 0, stream>>>(Y1, W2b, scale1, shift1, Y2, sum2, sumsq2);
    finalize_kernel<<<1, 128, 0, stream>>>(sum2, sumsq2, g2, b2, scale2, shift2, CC2);
    apply2_kernel<<<16384, 256, 0, stream>>>(Y2, scale2, shift2, out);
}